// Round 6
// baseline (693.660 us; speedup 1.0000x reference)
//
#include <hip/hip_runtime.h>
#include <hip/hip_cooperative_groups.h>
#include <cstddef>
#include <cstdint>

// Problem constants (fixed by the reference)
#define NN 50000      // nodes
#define EE 800000     // edges (before self loops)
#define ETOT (EE + NN)
#define FIN 128
#define D1 256        // HEADS*HID
#define HID 64
#define HEADS 4
#define NG 512
#define FOUT 64
#define NEG_SLOPE 0.2f

#define NBLK_NODES ((NN + 255) / 256)   // 196

typedef _Float16 f16x8 __attribute__((ext_vector_type(8)));
typedef _Float16 f16x4 __attribute__((ext_vector_type(4)));
typedef float f32x4 __attribute__((ext_vector_type(4)));

__device__ __forceinline__ float leaky(float x) { return x > 0.f ? x : NEG_SLOPE * x; }

// ---------------------------------------------------------------------------
// Cooperative single-kernel CSR build (replaces 6 dispatches):
// zero deg -> histogram -> per-chunk LDS scan -> partial scan -> add offsets
// -> scatter. 512 blocks x 256 thr (2 blocks/CU, co-resident).
// ---------------------------------------------------------------------------
#define CSR_GB 512

__global__ __launch_bounds__(256) void k_csr_coop(
    const int* __restrict__ ei, int* __restrict__ deg, int* __restrict__ row_off,
    int* __restrict__ part, int* __restrict__ cursor, int* __restrict__ csr_src) {
    namespace cg = cooperative_groups;
    cg::grid_group grid = cg::this_grid();
    __shared__ int sd[256];
    const int tid = threadIdx.x;
    const int bid = blockIdx.x;
    const int gstride = CSR_GB * 256;
    const int gidx = bid * 256 + tid;

    // phase 0: zero degree
    for (int i = gidx; i < NN; i += gstride) deg[i] = 0;
    grid.sync();
    // phase 1: histogram of dst
    for (int e = gidx; e < EE; e += gstride) atomicAdd(&deg[ei[EE + e]], 1);
    grid.sync();
    // phase 2: per-chunk exclusive scan (+1 self loop), chunk = 256 nodes
    for (int chunk = bid; chunk < NBLK_NODES; chunk += CSR_GB) {
        int i = chunk * 256 + tid;
        int v = (i < NN) ? deg[i] + 1 : 0;
        sd[tid] = v;
        __syncthreads();
        for (int off = 1; off < 256; off <<= 1) {
            int t = (tid >= off) ? sd[tid - off] : 0;
            __syncthreads();
            sd[tid] += t;
            __syncthreads();
        }
        if (i < NN) row_off[i] = sd[tid] - v;
        if (tid == 255) part[chunk] = sd[255];
        __syncthreads();
    }
    grid.sync();
    // phase 3: block 0 scans the 196 partials
    if (bid == 0) {
        int v = (tid < NBLK_NODES) ? part[tid] : 0;
        sd[tid] = v;
        __syncthreads();
        for (int off = 1; off < 256; off <<= 1) {
            int t = (tid >= off) ? sd[tid - off] : 0;
            __syncthreads();
            sd[tid] += t;
            __syncthreads();
        }
        part[tid] = sd[tid] - v;
    }
    grid.sync();
    // phase 4: add chunk offsets, init cursor
    for (int i = gidx; i < NN; i += gstride) {
        int r = row_off[i] + part[i >> 8];
        row_off[i] = r;
        cursor[i] = r;
    }
    if (gidx == 0) row_off[NN] = ETOT;
    grid.sync();
    // phase 5: scatter (edges + self loops)
    for (int i = gidx; i < ETOT; i += gstride) {
        int s, d;
        if (i < EE) { s = ei[i]; d = ei[EE + i]; }
        else        { s = d = i - EE; }
        int p = atomicAdd(&cursor[d], 1);
        csr_src[p] = s;
    }
}

// ---------------------------------------------------------------------------
// Weight transposes: W[K][256] fp32 -> Wt[256][K] fp16, both layers, 1 kernel
// ---------------------------------------------------------------------------
__global__ void k_cvt_w(const float* __restrict__ W1, const float* __restrict__ W2,
                        _Float16* __restrict__ w1t, _Float16* __restrict__ w2t) {
    int idx = blockIdx.x * 256 + threadIdx.x;
    if (idx < 256 * FIN) {
        int n = idx / FIN, k = idx - n * FIN;
        w1t[idx] = (_Float16)W1[(size_t)k * 256 + n];
    } else if (idx < 256 * FIN + 256 * D1) {
        int j = idx - 256 * FIN;
        int n = j >> 8, k = j & 255;
        w2t[j] = (_Float16)W2[(size_t)k * 256 + n];
    }
}

// ---------------------------------------------------------------------------
// MFMA fp16 GEMM (NT) with FUSED attention logits epilogue.
// C[M,256] = A[M,K] * Bt[256,K]^T, fp32 acc, fp16 out.
// BM=BN=128, BK=64; 4 waves 2x2; swapped-operand MFMA -> lane's 4 acc regs
// contiguous in n. Each wave's 64-ch slice == one head (head = 2*by + wn),
// so a_s/a_d for its 64 rows are computed wave-locally from fp32 acc.
// A is fp32 (layer 1, x) or fp16 (layer 2) via template.
// ---------------------------------------------------------------------------
#define BM 128
#define BN 128
#define BK 64
#define LDK (BK + 4)

template <int K, typename AT>
__global__ __launch_bounds__(256) void k_gemm(const AT* __restrict__ A,
                                              const _Float16* __restrict__ Bt,
                                              _Float16* __restrict__ C,
                                              const float* __restrict__ att_s,
                                              const float* __restrict__ att_d,
                                              float* __restrict__ a_s,
                                              float* __restrict__ a_d) {
    __shared__ _Float16 As[BM][LDK];
    __shared__ _Float16 Bs[BN][LDK];
    const int tid = threadIdx.x;
    const int lane = tid & 63;
    const int wave = tid >> 6;            // 0..3
    const int wm = wave & 1, wn = wave >> 1;
    const int m0 = blockIdx.x * BM;
    const int n0 = blockIdx.y * BN;
    const int row_m = lane & 15, quad = lane >> 4;

    f32x4 acc[4][4];
#pragma unroll
    for (int mi = 0; mi < 4; ++mi)
#pragma unroll
        for (int ni = 0; ni < 4; ++ni)
#pragma unroll
            for (int r = 0; r < 4; ++r) acc[mi][ni][r] = 0.f;

    const int c8 = (tid & 7) * 8;          // f16 column offset within row
    const int rr = tid >> 3;               // 0..31

    for (int k0 = 0; k0 < K; k0 += BK) {
#pragma unroll
        for (int p = 0; p < 4; ++p) {
            int r = p * 32 + rr;
            int gr = m0 + r; gr = gr < NN ? gr : NN - 1;
            f16x8 o;
            if constexpr (sizeof(AT) == 4) {
                const float4 v0 = *(const float4*)((const float*)A + (size_t)gr * K + k0 + c8);
                const float4 v1 = *(const float4*)((const float*)A + (size_t)gr * K + k0 + c8 + 4);
                o[0] = (_Float16)v0.x; o[1] = (_Float16)v0.y;
                o[2] = (_Float16)v0.z; o[3] = (_Float16)v0.w;
                o[4] = (_Float16)v1.x; o[5] = (_Float16)v1.y;
                o[6] = (_Float16)v1.z; o[7] = (_Float16)v1.w;
            } else {
                o = *(const f16x8*)((const _Float16*)A + (size_t)gr * K + k0 + c8);
            }
            *(f16x8*)(&As[r][c8]) = o;
        }
#pragma unroll
        for (int p = 0; p < 4; ++p) {
            int r = p * 32 + rr;
            f16x8 v = *(const f16x8*)(Bt + (size_t)(n0 + r) * K + k0 + c8);
            *(f16x8*)(&Bs[r][c8]) = v;
        }
        __syncthreads();
#pragma unroll
        for (int kc = 0; kc < BK; kc += 32) {
            f16x8 af[4], bf[4];
#pragma unroll
            for (int mi = 0; mi < 4; ++mi)
                af[mi] = *(const f16x8*)(&As[wm * 64 + mi * 16 + row_m][kc + quad * 8]);
#pragma unroll
            for (int ni = 0; ni < 4; ++ni)
                bf[ni] = *(const f16x8*)(&Bs[wn * 64 + ni * 16 + row_m][kc + quad * 8]);
            // swapped operands: D holds C^T fragment
#pragma unroll
            for (int mi = 0; mi < 4; ++mi)
#pragma unroll
                for (int ni = 0; ni < 4; ++ni)
                    acc[mi][ni] = __builtin_amdgcn_mfma_f32_16x16x32_f16(
                        bf[ni], af[mi], acc[mi][ni], 0, 0, 0);
        }
        __syncthreads();
    }
    // store C: value(lane, reg) of acc[mi][ni] =
    //   C[m0+wm*64+mi*16+row_m][n0+wn*64+ni*16+quad*4+reg]
#pragma unroll
    for (int mi = 0; mi < 4; ++mi) {
        int m = m0 + wm * 64 + mi * 16 + row_m;
        if (m < NN) {
#pragma unroll
            for (int ni = 0; ni < 4; ++ni) {
                f16x4 o;
                o[0] = (_Float16)acc[mi][ni][0];
                o[1] = (_Float16)acc[mi][ni][1];
                o[2] = (_Float16)acc[mi][ni][2];
                o[3] = (_Float16)acc[mi][ni][3];
                *(f16x4*)(C + (size_t)m * D1 + n0 + wn * 64 + ni * 16 + quad * 4) = o;
            }
        }
    }
    // fused logits: this wave's 64 channels == head (2*by + wn); local channel
    // of acc[mi][ni][r] is ni*16 + quad*4 + r.
    const int head = blockIdx.y * 2 + wn;
    const float* attsv = att_s + head * HID;
    const float* attdv = att_d + head * HID;
    float avs[4][4], avd[4][4];
#pragma unroll
    for (int ni = 0; ni < 4; ++ni)
#pragma unroll
        for (int r = 0; r < 4; ++r) {
            avs[ni][r] = attsv[ni * 16 + quad * 4 + r];
            avd[ni][r] = attdv[ni * 16 + quad * 4 + r];
        }
#pragma unroll
    for (int mi = 0; mi < 4; ++mi) {
        float ps = 0.f, pd = 0.f;
#pragma unroll
        for (int ni = 0; ni < 4; ++ni)
#pragma unroll
            for (int r = 0; r < 4; ++r) {
                ps += acc[mi][ni][r] * avs[ni][r];
                pd += acc[mi][ni][r] * avd[ni][r];
            }
        ps += __shfl_xor(ps, 16); ps += __shfl_xor(ps, 32);
        pd += __shfl_xor(pd, 16); pd += __shfl_xor(pd, 32);
        int m = m0 + wm * 64 + mi * 16 + row_m;
        if (quad == 0 && m < NN) {
            a_s[m * 4 + head] = ps;
            a_d[m * 4 + head] = pd;
        }
    }
}

// ---------------------------------------------------------------------------
// GAT softmax + aggregation (R3-proven structure): one wave per dst node,
// single pass (bounded logits, no max subtraction). lane t owns channels
// 4t..4t+3 (head = t>>4); weights via LDS; unroll-4 gather of f16x4 rows.
// ---------------------------------------------------------------------------
__global__ __launch_bounds__(64) void k_aggregate(
    const _Float16* __restrict__ h, const float* __restrict__ a_s,
    const float* __restrict__ a_d, const int* __restrict__ row_off,
    const int* __restrict__ csr_src, const float* __restrict__ bias,
    _Float16* __restrict__ out, int apply_elu) {
    const int n = blockIdx.x;
    const int tid = threadIdx.x;              // 0..63
    const int myhead = tid >> 4;
    const int start = row_off[n];
    const int end = row_off[n + 1];

    __shared__ float s_w[64][4];
    __shared__ int s_src[64];

    const float4 ad = *(const float4*)(a_d + (size_t)n * 4);

    float l0 = 0.f, l1 = 0.f, l2 = 0.f, l3 = 0.f;
    float4 acc = make_float4(0.f, 0.f, 0.f, 0.f);
    const int c4 = tid * 4;
    for (int base = start; base < end; base += 64) {
        int len = min(64, end - base);
        if (tid < len) {
            int s = csr_src[base + tid];
            const float4 as = *(const float4*)(a_s + (size_t)s * 4);
            float x0 = __expf(leaky(as.x + ad.x));
            float x1 = __expf(leaky(as.y + ad.y));
            float x2 = __expf(leaky(as.z + ad.z));
            float x3 = __expf(leaky(as.w + ad.w));
            l0 += x0; l1 += x1; l2 += x2; l3 += x3;
            s_src[tid] = s;
            s_w[tid][0] = x0; s_w[tid][1] = x1; s_w[tid][2] = x2; s_w[tid][3] = x3;
        }
        __syncthreads();
#pragma unroll 4
        for (int jj = 0; jj < len; ++jj) {
            float wgt = s_w[jj][myhead];
            const f16x4 hv = *(const f16x4*)(h + (size_t)s_src[jj] * D1 + c4);
            acc.x += wgt * (float)hv[0];
            acc.y += wgt * (float)hv[1];
            acc.z += wgt * (float)hv[2];
            acc.w += wgt * (float)hv[3];
        }
        __syncthreads();
    }
#pragma unroll
    for (int off = 32; off > 0; off >>= 1) {
        l0 += __shfl_down(l0, off);
        l1 += __shfl_down(l1, off);
        l2 += __shfl_down(l2, off);
        l3 += __shfl_down(l3, off);
    }
    l0 = __shfl(l0, 0); l1 = __shfl(l1, 0); l2 = __shfl(l2, 0); l3 = __shfl(l3, 0);
    float denom = (myhead == 0) ? l0 : (myhead == 1) ? l1 : (myhead == 2) ? l2 : l3;
    float inv = 1.f / denom;

    const float4 bb = *(const float4*)(bias + c4);
    float vx = acc.x * inv + bb.x;
    float vy = acc.y * inv + bb.y;
    float vz = acc.z * inv + bb.z;
    float vw = acc.w * inv + bb.w;
    if (apply_elu) {
        vx = vx > 0.f ? vx : expm1f(vx);
        vy = vy > 0.f ? vy : expm1f(vy);
        vz = vz > 0.f ? vz : expm1f(vz);
        vw = vw > 0.f ? vw : expm1f(vw);
    }
    f16x4 o;
    o[0] = (_Float16)vx; o[1] = (_Float16)vy; o[2] = (_Float16)vz; o[3] = (_Float16)vw;
    *(f16x4*)(out + (size_t)n * D1 + c4) = o;
}

// ---------------------------------------------------------------------------
// Fused global mean pool + final FC: one 256-thr block per graph.
// batch is sorted -> binary search node range; channel-per-thread sum;
// then threads 0..63 compute the FC row.
// ---------------------------------------------------------------------------
__global__ __launch_bounds__(256) void k_pool_fc(const _Float16* __restrict__ h,
                                                 const int* __restrict__ batch,
                                                 const float* __restrict__ fc_w,
                                                 const float* __restrict__ fc_b,
                                                 float* __restrict__ out) {
    __shared__ float row[D1];
    int g = blockIdx.x, c = threadIdx.x;
    int lo = 0, hi = NN;
    while (lo < hi) { int mid = (lo + hi) >> 1; if (batch[mid] < g) lo = mid + 1; else hi = mid; }
    int start = lo;
    hi = NN;
    while (lo < hi) { int mid = (lo + hi) >> 1; if (batch[mid] < g + 1) lo = mid + 1; else hi = mid; }
    int end = lo;

    float acc = 0.f;
    for (int n = start; n < end; ++n) acc += (float)h[(size_t)n * D1 + c];
    float inv = 1.f / fmaxf((float)(end - start), 1.f);
    row[c] = acc * inv;
    __syncthreads();
    if (c < FOUT) {
        float o = 0.f;
#pragma unroll 4
        for (int k = 0; k < D1; ++k) o += row[k] * fc_w[k * FOUT + c];
        out[(size_t)g * FOUT + c] = o + fc_b[c];
    }
}

// ---------------------------------------------------------------------------
extern "C" void kernel_launch(void* const* d_in, const int* in_sizes, int n_in,
                              void* d_out, int out_size, void* d_ws, size_t ws_size,
                              hipStream_t stream) {
    const float* x        = (const float*)d_in[0];
    const int*   ei       = (const int*)d_in[1];
    const int*   batch    = (const int*)d_in[2];
    const float* W1       = (const float*)d_in[3];
    const float* att_src1 = (const float*)d_in[4];
    const float* att_dst1 = (const float*)d_in[5];
    const float* b1       = (const float*)d_in[6];
    const float* W2       = (const float*)d_in[7];
    const float* att_src2 = (const float*)d_in[8];
    const float* att_dst2 = (const float*)d_in[9];
    const float* b2       = (const float*)d_in[10];
    const float* fc_w     = (const float*)d_in[11];
    const float* fc_b     = (const float*)d_in[12];
    float* out = (float*)d_out;

    // workspace carve-up (~58 MB)
    _Float16* h_pre  = (_Float16*)d_ws;                       // NN*D1 f16
    _Float16* h_act  = h_pre + (size_t)NN * D1;               // NN*D1 f16
    _Float16* w1t    = h_act + (size_t)NN * D1;               // 256*128
    _Float16* w2t    = w1t + 256 * FIN;                       // 256*256
    float* a_s       = (float*)(w2t + 256 * D1);
    float* a_d       = a_s + (size_t)NN * 4;
    int*   deg       = (int*)(a_d + (size_t)NN * 4);
    int*   row_off   = deg + NN;
    int*   cursor    = row_off + NN + 1;
    int*   part      = cursor + NN;
    int*   csr_src   = part + 256;

    // ---- CSR build (single cooperative dispatch) ----
    {
        void* args[] = {(void*)&ei, (void*)&deg, (void*)&row_off,
                        (void*)&part, (void*)&cursor, (void*)&csr_src};
        hipLaunchCooperativeKernel((const void*)k_csr_coop, dim3(CSR_GB), dim3(256),
                                   args, 0, stream);
    }

    // ---- weight transposes (1 dispatch) ----
    k_cvt_w<<<(256 * (FIN + D1) + 255) / 256, 256, 0, stream>>>(W1, W2, w1t, w2t);

    dim3 ggrid((NN + BM - 1) / BM, D1 / BN);

    // ---- layer 1 (GEMM + fused logits) ----
    k_gemm<FIN, float><<<ggrid, 256, 0, stream>>>(x, w1t, h_pre,
                                                  att_src1, att_dst1, a_s, a_d);
    k_aggregate<<<NN, 64, 0, stream>>>(h_pre, a_s, a_d, row_off, csr_src, b1, h_act, 1);

    // ---- layer 2 (GEMM + fused logits) ----
    k_gemm<D1, _Float16><<<ggrid, 256, 0, stream>>>(h_act, w2t, h_pre,
                                                    att_src2, att_dst2, a_s, a_d);
    k_aggregate<<<NN, 64, 0, stream>>>(h_pre, a_s, a_d, row_off, csr_src, b2, h_act, 1);

    // ---- fused pool + fc ----
    k_pool_fc<<<NG, 256, 0, stream>>>(h_act, batch, fc_w, fc_b, out);
}

// Round 7
// 407.149 us; speedup vs baseline: 1.7037x; 1.7037x over previous
//
#include <hip/hip_runtime.h>
#include <cstddef>
#include <cstdint>

// Problem constants (fixed by the reference)
#define NN 50000      // nodes
#define EE 800000     // edges (before self loops)
#define ETOT (EE + NN)
#define FIN 128
#define D1 256        // HEADS*HID
#define HID 64
#define HEADS 4
#define NG 512
#define FOUT 64
#define NEG_SLOPE 0.2f

typedef _Float16 f16x8 __attribute__((ext_vector_type(8)));
typedef _Float16 f16x4 __attribute__((ext_vector_type(4)));
typedef float f32x4 __attribute__((ext_vector_type(4)));

__device__ __forceinline__ float leaky(float x) { return x > 0.f ? x : NEG_SLOPE * x; }

// ---------------------------------------------------------------------------
// CSR build: histogram, 2-level exclusive scan (+1 self loop), scatter
// (6 small dispatches — measured cheaper than a cooperative single-kernel
//  version, whose 5 grid.sync()s cost ~70 µs each: R6 post-mortem)
// ---------------------------------------------------------------------------
__global__ void k_hist(const int* __restrict__ ei, int* __restrict__ deg) {
    int e = blockIdx.x * 256 + threadIdx.x;
    if (e < EE) atomicAdd(&deg[ei[EE + e]], 1);   // dst row
}

__global__ void k_scan_blocks(const int* __restrict__ deg, int* __restrict__ row_off,
                              int* __restrict__ part) {
    __shared__ int sd[256];
    int tid = threadIdx.x;
    int i = blockIdx.x * 256 + tid;
    int v = (i < NN) ? deg[i] + 1 : 0;              // +1: self loop
    sd[tid] = v;
    __syncthreads();
    for (int off = 1; off < 256; off <<= 1) {
        int t = (tid >= off) ? sd[tid - off] : 0;
        __syncthreads();
        sd[tid] += t;
        __syncthreads();
    }
    if (i < NN) row_off[i] = sd[tid] - v;           // exclusive within block
    if (tid == 255) part[blockIdx.x] = sd[255];     // block total
}

__global__ void k_scan_part(int* __restrict__ part) {
    __shared__ int sd[256];
    int tid = threadIdx.x;
    int nblk = (NN + 255) / 256;
    int v = (tid < nblk) ? part[tid] : 0;
    sd[tid] = v;
    __syncthreads();
    for (int off = 1; off < 256; off <<= 1) {
        int t = (tid >= off) ? sd[tid - off] : 0;
        __syncthreads();
        sd[tid] += t;
        __syncthreads();
    }
    part[tid] = sd[tid] - v;                        // exclusive block offsets
}

__global__ void k_add_off(int* __restrict__ row_off, const int* __restrict__ part,
                          int* __restrict__ cursor) {
    int i = blockIdx.x * 256 + threadIdx.x;
    if (i < NN) {
        int r = row_off[i] + part[blockIdx.x];
        row_off[i] = r;
        cursor[i] = r;
    }
    if (i == 0) row_off[NN] = ETOT;
}

__global__ void k_scatter(const int* __restrict__ ei, int* __restrict__ cursor,
                          int* __restrict__ csr_src) {
    int i = blockIdx.x * 256 + threadIdx.x;
    if (i < ETOT) {
        int s, d;
        if (i < EE) { s = ei[i]; d = ei[EE + i]; }
        else        { s = d = i - EE; }
        int p = atomicAdd(&cursor[d], 1);
        csr_src[p] = s;
    }
}

// ---------------------------------------------------------------------------
// Weight transposes: W[K][256] fp32 -> Wt[256][K] fp16, both layers, 1 kernel
// ---------------------------------------------------------------------------
__global__ void k_cvt_w(const float* __restrict__ W1, const float* __restrict__ W2,
                        _Float16* __restrict__ w1t, _Float16* __restrict__ w2t) {
    int idx = blockIdx.x * 256 + threadIdx.x;
    if (idx < 256 * FIN) {
        int n = idx / FIN, k = idx - n * FIN;
        w1t[idx] = (_Float16)W1[(size_t)k * 256 + n];
    } else if (idx < 256 * FIN + 256 * D1) {
        int j = idx - 256 * FIN;
        int n = j >> 8, k = j & 255;
        w2t[j] = (_Float16)W2[(size_t)k * 256 + n];
    }
}

// ---------------------------------------------------------------------------
// MFMA fp16 GEMM (NT) with FUSED attention logits epilogue.
// C[M,256] = A[M,K] * Bt[256,K]^T, fp32 acc, fp16 out.
// BM=BN=128, BK=64; 4 waves 2x2; swapped-operand MFMA -> lane's 4 acc regs
// contiguous in n. Each wave's 64-ch slice == one head (head = 2*by + wn),
// so a_s/a_d for its 64 rows are computed wave-locally from fp32 acc.
// A is fp32 (layer 1, x) or fp16 (layer 2) via template.
// ---------------------------------------------------------------------------
#define BM 128
#define BN 128
#define BK 64
#define LDK (BK + 4)

template <int K, typename AT>
__global__ __launch_bounds__(256) void k_gemm(const AT* __restrict__ A,
                                              const _Float16* __restrict__ Bt,
                                              _Float16* __restrict__ C,
                                              const float* __restrict__ att_s,
                                              const float* __restrict__ att_d,
                                              float* __restrict__ a_s,
                                              float* __restrict__ a_d) {
    __shared__ _Float16 As[BM][LDK];
    __shared__ _Float16 Bs[BN][LDK];
    const int tid = threadIdx.x;
    const int lane = tid & 63;
    const int wave = tid >> 6;            // 0..3
    const int wm = wave & 1, wn = wave >> 1;
    const int m0 = blockIdx.x * BM;
    const int n0 = blockIdx.y * BN;
    const int row_m = lane & 15, quad = lane >> 4;

    f32x4 acc[4][4];
#pragma unroll
    for (int mi = 0; mi < 4; ++mi)
#pragma unroll
        for (int ni = 0; ni < 4; ++ni)
#pragma unroll
            for (int r = 0; r < 4; ++r) acc[mi][ni][r] = 0.f;

    const int c8 = (tid & 7) * 8;          // f16 column offset within row
    const int rr = tid >> 3;               // 0..31

    for (int k0 = 0; k0 < K; k0 += BK) {
#pragma unroll
        for (int p = 0; p < 4; ++p) {
            int r = p * 32 + rr;
            int gr = m0 + r; gr = gr < NN ? gr : NN - 1;
            f16x8 o;
            if constexpr (sizeof(AT) == 4) {
                const float4 v0 = *(const float4*)((const float*)A + (size_t)gr * K + k0 + c8);
                const float4 v1 = *(const float4*)((const float*)A + (size_t)gr * K + k0 + c8 + 4);
                o[0] = (_Float16)v0.x; o[1] = (_Float16)v0.y;
                o[2] = (_Float16)v0.z; o[3] = (_Float16)v0.w;
                o[4] = (_Float16)v1.x; o[5] = (_Float16)v1.y;
                o[6] = (_Float16)v1.z; o[7] = (_Float16)v1.w;
            } else {
                o = *(const f16x8*)((const _Float16*)A + (size_t)gr * K + k0 + c8);
            }
            *(f16x8*)(&As[r][c8]) = o;
        }
#pragma unroll
        for (int p = 0; p < 4; ++p) {
            int r = p * 32 + rr;
            f16x8 v = *(const f16x8*)(Bt + (size_t)(n0 + r) * K + k0 + c8);
            *(f16x8*)(&Bs[r][c8]) = v;
        }
        __syncthreads();
#pragma unroll
        for (int kc = 0; kc < BK; kc += 32) {
            f16x8 af[4], bf[4];
#pragma unroll
            for (int mi = 0; mi < 4; ++mi)
                af[mi] = *(const f16x8*)(&As[wm * 64 + mi * 16 + row_m][kc + quad * 8]);
#pragma unroll
            for (int ni = 0; ni < 4; ++ni)
                bf[ni] = *(const f16x8*)(&Bs[wn * 64 + ni * 16 + row_m][kc + quad * 8]);
            // swapped operands: D holds C^T fragment
#pragma unroll
            for (int mi = 0; mi < 4; ++mi)
#pragma unroll
                for (int ni = 0; ni < 4; ++ni)
                    acc[mi][ni] = __builtin_amdgcn_mfma_f32_16x16x32_f16(
                        bf[ni], af[mi], acc[mi][ni], 0, 0, 0);
        }
        __syncthreads();
    }
    // store C: value(lane, reg) of acc[mi][ni] =
    //   C[m0+wm*64+mi*16+row_m][n0+wn*64+ni*16+quad*4+reg]
#pragma unroll
    for (int mi = 0; mi < 4; ++mi) {
        int m = m0 + wm * 64 + mi * 16 + row_m;
        if (m < NN) {
#pragma unroll
            for (int ni = 0; ni < 4; ++ni) {
                f16x4 o;
                o[0] = (_Float16)acc[mi][ni][0];
                o[1] = (_Float16)acc[mi][ni][1];
                o[2] = (_Float16)acc[mi][ni][2];
                o[3] = (_Float16)acc[mi][ni][3];
                *(f16x4*)(C + (size_t)m * D1 + n0 + wn * 64 + ni * 16 + quad * 4) = o;
            }
        }
    }
    // fused logits: this wave's 64 channels == head (2*by + wn); local channel
    // of acc[mi][ni][r] is ni*16 + quad*4 + r.
    const int head = blockIdx.y * 2 + wn;
    const float* attsv = att_s + head * HID;
    const float* attdv = att_d + head * HID;
    float avs[4][4], avd[4][4];
#pragma unroll
    for (int ni = 0; ni < 4; ++ni)
#pragma unroll
        for (int r = 0; r < 4; ++r) {
            avs[ni][r] = attsv[ni * 16 + quad * 4 + r];
            avd[ni][r] = attdv[ni * 16 + quad * 4 + r];
        }
#pragma unroll
    for (int mi = 0; mi < 4; ++mi) {
        float ps = 0.f, pd = 0.f;
#pragma unroll
        for (int ni = 0; ni < 4; ++ni)
#pragma unroll
            for (int r = 0; r < 4; ++r) {
                ps += acc[mi][ni][r] * avs[ni][r];
                pd += acc[mi][ni][r] * avd[ni][r];
            }
        ps += __shfl_xor(ps, 16); ps += __shfl_xor(ps, 32);
        pd += __shfl_xor(pd, 16); pd += __shfl_xor(pd, 32);
        int m = m0 + wm * 64 + mi * 16 + row_m;
        if (quad == 0 && m < NN) {
            a_s[m * 4 + head] = ps;
            a_d[m * 4 + head] = pd;
        }
    }
}

// ---------------------------------------------------------------------------
// GAT softmax + aggregation (R3-proven structure): one wave per dst node,
// single pass (bounded logits, no max subtraction). lane t owns channels
// 4t..4t+3 (head = t>>4); weights via LDS; unroll-4 gather of f16x4 rows.
// ---------------------------------------------------------------------------
__global__ __launch_bounds__(64) void k_aggregate(
    const _Float16* __restrict__ h, const float* __restrict__ a_s,
    const float* __restrict__ a_d, const int* __restrict__ row_off,
    const int* __restrict__ csr_src, const float* __restrict__ bias,
    _Float16* __restrict__ out, int apply_elu) {
    const int n = blockIdx.x;
    const int tid = threadIdx.x;              // 0..63
    const int myhead = tid >> 4;
    const int start = row_off[n];
    const int end = row_off[n + 1];

    __shared__ float s_w[64][4];
    __shared__ int s_src[64];

    const float4 ad = *(const float4*)(a_d + (size_t)n * 4);

    float l0 = 0.f, l1 = 0.f, l2 = 0.f, l3 = 0.f;
    float4 acc = make_float4(0.f, 0.f, 0.f, 0.f);
    const int c4 = tid * 4;
    for (int base = start; base < end; base += 64) {
        int len = min(64, end - base);
        if (tid < len) {
            int s = csr_src[base + tid];
            const float4 as = *(const float4*)(a_s + (size_t)s * 4);
            float x0 = __expf(leaky(as.x + ad.x));
            float x1 = __expf(leaky(as.y + ad.y));
            float x2 = __expf(leaky(as.z + ad.z));
            float x3 = __expf(leaky(as.w + ad.w));
            l0 += x0; l1 += x1; l2 += x2; l3 += x3;
            s_src[tid] = s;
            s_w[tid][0] = x0; s_w[tid][1] = x1; s_w[tid][2] = x2; s_w[tid][3] = x3;
        }
        __syncthreads();
#pragma unroll 4
        for (int jj = 0; jj < len; ++jj) {
            float wgt = s_w[jj][myhead];
            const f16x4 hv = *(const f16x4*)(h + (size_t)s_src[jj] * D1 + c4);
            acc.x += wgt * (float)hv[0];
            acc.y += wgt * (float)hv[1];
            acc.z += wgt * (float)hv[2];
            acc.w += wgt * (float)hv[3];
        }
        __syncthreads();
    }
#pragma unroll
    for (int off = 32; off > 0; off >>= 1) {
        l0 += __shfl_down(l0, off);
        l1 += __shfl_down(l1, off);
        l2 += __shfl_down(l2, off);
        l3 += __shfl_down(l3, off);
    }
    l0 = __shfl(l0, 0); l1 = __shfl(l1, 0); l2 = __shfl(l2, 0); l3 = __shfl(l3, 0);
    float denom = (myhead == 0) ? l0 : (myhead == 1) ? l1 : (myhead == 2) ? l2 : l3;
    float inv = 1.f / denom;

    const float4 bb = *(const float4*)(bias + c4);
    float vx = acc.x * inv + bb.x;
    float vy = acc.y * inv + bb.y;
    float vz = acc.z * inv + bb.z;
    float vw = acc.w * inv + bb.w;
    if (apply_elu) {
        vx = vx > 0.f ? vx : expm1f(vx);
        vy = vy > 0.f ? vy : expm1f(vy);
        vz = vz > 0.f ? vz : expm1f(vz);
        vw = vw > 0.f ? vw : expm1f(vw);
    }
    f16x4 o;
    o[0] = (_Float16)vx; o[1] = (_Float16)vy; o[2] = (_Float16)vz; o[3] = (_Float16)vw;
    *(f16x4*)(out + (size_t)n * D1 + c4) = o;
}

// ---------------------------------------------------------------------------
// Fused global mean pool + final FC: one 256-thr block per graph.
// batch is sorted -> binary search node range; channel-per-thread sum;
// then threads 0..63 compute the FC row.
// ---------------------------------------------------------------------------
__global__ __launch_bounds__(256) void k_pool_fc(const _Float16* __restrict__ h,
                                                 const int* __restrict__ batch,
                                                 const float* __restrict__ fc_w,
                                                 const float* __restrict__ fc_b,
                                                 float* __restrict__ out) {
    __shared__ float row[D1];
    int g = blockIdx.x, c = threadIdx.x;
    int lo = 0, hi = NN;
    while (lo < hi) { int mid = (lo + hi) >> 1; if (batch[mid] < g) lo = mid + 1; else hi = mid; }
    int start = lo;
    hi = NN;
    while (lo < hi) { int mid = (lo + hi) >> 1; if (batch[mid] < g + 1) lo = mid + 1; else hi = mid; }
    int end = lo;

    float acc = 0.f;
    for (int n = start; n < end; ++n) acc += (float)h[(size_t)n * D1 + c];
    float inv = 1.f / fmaxf((float)(end - start), 1.f);
    row[c] = acc * inv;
    __syncthreads();
    if (c < FOUT) {
        float o = 0.f;
#pragma unroll 4
        for (int k = 0; k < D1; ++k) o += row[k] * fc_w[k * FOUT + c];
        out[(size_t)g * FOUT + c] = o + fc_b[c];
    }
}

// ---------------------------------------------------------------------------
extern "C" void kernel_launch(void* const* d_in, const int* in_sizes, int n_in,
                              void* d_out, int out_size, void* d_ws, size_t ws_size,
                              hipStream_t stream) {
    const float* x        = (const float*)d_in[0];
    const int*   ei       = (const int*)d_in[1];
    const int*   batch    = (const int*)d_in[2];
    const float* W1       = (const float*)d_in[3];
    const float* att_src1 = (const float*)d_in[4];
    const float* att_dst1 = (const float*)d_in[5];
    const float* b1       = (const float*)d_in[6];
    const float* W2       = (const float*)d_in[7];
    const float* att_src2 = (const float*)d_in[8];
    const float* att_dst2 = (const float*)d_in[9];
    const float* b2       = (const float*)d_in[10];
    const float* fc_w     = (const float*)d_in[11];
    const float* fc_b     = (const float*)d_in[12];
    float* out = (float*)d_out;

    // workspace carve-up (~58 MB)
    _Float16* h_pre  = (_Float16*)d_ws;                       // NN*D1 f16
    _Float16* h_act  = h_pre + (size_t)NN * D1;               // NN*D1 f16
    _Float16* w1t    = h_act + (size_t)NN * D1;               // 256*128
    _Float16* w2t    = w1t + 256 * FIN;                       // 256*256
    float* a_s       = (float*)(w2t + 256 * D1);
    float* a_d       = a_s + (size_t)NN * 4;
    int*   deg       = (int*)(a_d + (size_t)NN * 4);
    int*   row_off   = deg + NN;
    int*   cursor    = row_off + NN + 1;
    int*   part      = cursor + NN;
    int*   csr_src   = part + 256;

    const int nblk_nodes = (NN + 255) / 256;
    const int nblk_edges = (EE + 255) / 256;
    const int nblk_etot  = (ETOT + 255) / 256;

    // ---- CSR build (6 small dispatches) ----
    hipMemsetAsync(deg, 0, NN * sizeof(int), stream);
    k_hist<<<nblk_edges, 256, 0, stream>>>(ei, deg);
    k_scan_blocks<<<nblk_nodes, 256, 0, stream>>>(deg, row_off, part);
    k_scan_part<<<1, 256, 0, stream>>>(part);
    k_add_off<<<nblk_nodes, 256, 0, stream>>>(row_off, part, cursor);
    k_scatter<<<nblk_etot, 256, 0, stream>>>(ei, cursor, csr_src);

    // ---- weight transposes (1 dispatch) ----
    k_cvt_w<<<(256 * (FIN + D1) + 255) / 256, 256, 0, stream>>>(W1, W2, w1t, w2t);

    dim3 ggrid((NN + BM - 1) / BM, D1 / BN);

    // ---- layer 1 (GEMM + fused logits) ----
    k_gemm<FIN, float><<<ggrid, 256, 0, stream>>>(x, w1t, h_pre,
                                                  att_src1, att_dst1, a_s, a_d);
    k_aggregate<<<NN, 64, 0, stream>>>(h_pre, a_s, a_d, row_off, csr_src, b1, h_act, 1);

    // ---- layer 2 (GEMM + fused logits) ----
    k_gemm<D1, _Float16><<<ggrid, 256, 0, stream>>>(h_act, w2t, h_pre,
                                                    att_src2, att_dst2, a_s, a_d);
    k_aggregate<<<NN, 64, 0, stream>>>(h_pre, a_s, a_d, row_off, csr_src, b2, h_act, 1);

    // ---- fused pool + fc ----
    k_pool_fc<<<NG, 256, 0, stream>>>(h_act, batch, fc_w, fc_b, out);
}

// Round 8
// 395.728 us; speedup vs baseline: 1.7529x; 1.0289x over previous
//
#include <hip/hip_runtime.h>
#include <cstddef>
#include <cstdint>

// Problem constants (fixed by the reference)
#define NN 50000      // nodes
#define EE 800000     // edges (before self loops)
#define ETOT (EE + NN)
#define FIN 128
#define D1 256        // HEADS*HID
#define HID 64
#define HEADS 4
#define NG 512
#define FOUT 64
#define NEG_SLOPE 0.2f

typedef _Float16 f16x8 __attribute__((ext_vector_type(8)));
typedef _Float16 f16x4 __attribute__((ext_vector_type(4)));
typedef float f32x4 __attribute__((ext_vector_type(4)));

__device__ __forceinline__ float leaky(float x) { return x > 0.f ? x : NEG_SLOPE * x; }

// ---------------------------------------------------------------------------
// CSR build: histogram, 2-level exclusive scan (+1 self loop), scatter
// (6 small dispatches — measured cheaper than a cooperative single-kernel
//  version, whose 5 grid.sync()s cost ~70 µs each: R6 post-mortem)
// ---------------------------------------------------------------------------
__global__ void k_hist(const int* __restrict__ ei, int* __restrict__ deg) {
    int e = blockIdx.x * 256 + threadIdx.x;
    if (e < EE) atomicAdd(&deg[ei[EE + e]], 1);   // dst row
}

__global__ void k_scan_blocks(const int* __restrict__ deg, int* __restrict__ row_off,
                              int* __restrict__ part) {
    __shared__ int sd[256];
    int tid = threadIdx.x;
    int i = blockIdx.x * 256 + tid;
    int v = (i < NN) ? deg[i] + 1 : 0;              // +1: self loop
    sd[tid] = v;
    __syncthreads();
    for (int off = 1; off < 256; off <<= 1) {
        int t = (tid >= off) ? sd[tid - off] : 0;
        __syncthreads();
        sd[tid] += t;
        __syncthreads();
    }
    if (i < NN) row_off[i] = sd[tid] - v;           // exclusive within block
    if (tid == 255) part[blockIdx.x] = sd[255];     // block total
}

__global__ void k_scan_part(int* __restrict__ part) {
    __shared__ int sd[256];
    int tid = threadIdx.x;
    int nblk = (NN + 255) / 256;
    int v = (tid < nblk) ? part[tid] : 0;
    sd[tid] = v;
    __syncthreads();
    for (int off = 1; off < 256; off <<= 1) {
        int t = (tid >= off) ? sd[tid - off] : 0;
        __syncthreads();
        sd[tid] += t;
        __syncthreads();
    }
    part[tid] = sd[tid] - v;                        // exclusive block offsets
}

__global__ void k_add_off(int* __restrict__ row_off, const int* __restrict__ part,
                          int* __restrict__ cursor) {
    int i = blockIdx.x * 256 + threadIdx.x;
    if (i < NN) {
        int r = row_off[i] + part[blockIdx.x];
        row_off[i] = r;
        cursor[i] = r;
    }
    if (i == 0) row_off[NN] = ETOT;
}

__global__ void k_scatter(const int* __restrict__ ei, int* __restrict__ cursor,
                          int* __restrict__ csr_src) {
    int i = blockIdx.x * 256 + threadIdx.x;
    if (i < ETOT) {
        int s, d;
        if (i < EE) { s = ei[i]; d = ei[EE + i]; }
        else        { s = d = i - EE; }
        int p = atomicAdd(&cursor[d], 1);
        csr_src[p] = s;
    }
}

// ---------------------------------------------------------------------------
// Weight transposes: W[K][256] fp32 -> Wt[256][K] fp16, both layers, 1 kernel
// ---------------------------------------------------------------------------
__global__ void k_cvt_w(const float* __restrict__ W1, const float* __restrict__ W2,
                        _Float16* __restrict__ w1t, _Float16* __restrict__ w2t) {
    int idx = blockIdx.x * 256 + threadIdx.x;
    if (idx < 256 * FIN) {
        int n = idx / FIN, k = idx - n * FIN;
        w1t[idx] = (_Float16)W1[(size_t)k * 256 + n];
    } else if (idx < 256 * FIN + 256 * D1) {
        int j = idx - 256 * FIN;
        int n = j >> 8, k = j & 255;
        w2t[j] = (_Float16)W2[(size_t)k * 256 + n];
    }
}

// ---------------------------------------------------------------------------
// MFMA fp16 GEMM (NT) with FUSED attention logits epilogue.
// C[M,256] = A[M,K] * Bt[256,K]^T, fp32 acc, fp16 out.
// BM=BN=128, BK=64; 4 waves 2x2; swapped-operand MFMA -> lane's 4 acc regs
// contiguous in n. Each wave's 64-ch slice == one head (head = 2*by + wn),
// so a_s/a_d for its 64 rows are computed wave-locally from fp32 acc.
// A is fp32 (layer 1, x) or fp16 (layer 2) via template.
// ---------------------------------------------------------------------------
#define BM 128
#define BN 128
#define BK 64
#define LDK (BK + 4)

template <int K, typename AT>
__global__ __launch_bounds__(256) void k_gemm(const AT* __restrict__ A,
                                              const _Float16* __restrict__ Bt,
                                              _Float16* __restrict__ C,
                                              const float* __restrict__ att_s,
                                              const float* __restrict__ att_d,
                                              float* __restrict__ a_s,
                                              float* __restrict__ a_d) {
    __shared__ _Float16 As[BM][LDK];
    __shared__ _Float16 Bs[BN][LDK];
    const int tid = threadIdx.x;
    const int lane = tid & 63;
    const int wave = tid >> 6;            // 0..3
    const int wm = wave & 1, wn = wave >> 1;
    const int m0 = blockIdx.x * BM;
    const int n0 = blockIdx.y * BN;
    const int row_m = lane & 15, quad = lane >> 4;

    f32x4 acc[4][4];
#pragma unroll
    for (int mi = 0; mi < 4; ++mi)
#pragma unroll
        for (int ni = 0; ni < 4; ++ni)
#pragma unroll
            for (int r = 0; r < 4; ++r) acc[mi][ni][r] = 0.f;

    const int c8 = (tid & 7) * 8;          // f16 column offset within row
    const int rr = tid >> 3;               // 0..31

    for (int k0 = 0; k0 < K; k0 += BK) {
#pragma unroll
        for (int p = 0; p < 4; ++p) {
            int r = p * 32 + rr;
            int gr = m0 + r; gr = gr < NN ? gr : NN - 1;
            f16x8 o;
            if constexpr (sizeof(AT) == 4) {
                const float4 v0 = *(const float4*)((const float*)A + (size_t)gr * K + k0 + c8);
                const float4 v1 = *(const float4*)((const float*)A + (size_t)gr * K + k0 + c8 + 4);
                o[0] = (_Float16)v0.x; o[1] = (_Float16)v0.y;
                o[2] = (_Float16)v0.z; o[3] = (_Float16)v0.w;
                o[4] = (_Float16)v1.x; o[5] = (_Float16)v1.y;
                o[6] = (_Float16)v1.z; o[7] = (_Float16)v1.w;
            } else {
                o = *(const f16x8*)((const _Float16*)A + (size_t)gr * K + k0 + c8);
            }
            *(f16x8*)(&As[r][c8]) = o;
        }
#pragma unroll
        for (int p = 0; p < 4; ++p) {
            int r = p * 32 + rr;
            f16x8 v = *(const f16x8*)(Bt + (size_t)(n0 + r) * K + k0 + c8);
            *(f16x8*)(&Bs[r][c8]) = v;
        }
        __syncthreads();
#pragma unroll
        for (int kc = 0; kc < BK; kc += 32) {
            f16x8 af[4], bf[4];
#pragma unroll
            for (int mi = 0; mi < 4; ++mi)
                af[mi] = *(const f16x8*)(&As[wm * 64 + mi * 16 + row_m][kc + quad * 8]);
#pragma unroll
            for (int ni = 0; ni < 4; ++ni)
                bf[ni] = *(const f16x8*)(&Bs[wn * 64 + ni * 16 + row_m][kc + quad * 8]);
            // swapped operands: D holds C^T fragment
#pragma unroll
            for (int mi = 0; mi < 4; ++mi)
#pragma unroll
                for (int ni = 0; ni < 4; ++ni)
                    acc[mi][ni] = __builtin_amdgcn_mfma_f32_16x16x32_f16(
                        bf[ni], af[mi], acc[mi][ni], 0, 0, 0);
        }
        __syncthreads();
    }
    // store C: value(lane, reg) of acc[mi][ni] =
    //   C[m0+wm*64+mi*16+row_m][n0+wn*64+ni*16+quad*4+reg]
#pragma unroll
    for (int mi = 0; mi < 4; ++mi) {
        int m = m0 + wm * 64 + mi * 16 + row_m;
        if (m < NN) {
#pragma unroll
            for (int ni = 0; ni < 4; ++ni) {
                f16x4 o;
                o[0] = (_Float16)acc[mi][ni][0];
                o[1] = (_Float16)acc[mi][ni][1];
                o[2] = (_Float16)acc[mi][ni][2];
                o[3] = (_Float16)acc[mi][ni][3];
                *(f16x4*)(C + (size_t)m * D1 + n0 + wn * 64 + ni * 16 + quad * 4) = o;
            }
        }
    }
    // fused logits: this wave's 64 channels == head (2*by + wn); local channel
    // of acc[mi][ni][r] is ni*16 + quad*4 + r.
    const int head = blockIdx.y * 2 + wn;
    const float* attsv = att_s + head * HID;
    const float* attdv = att_d + head * HID;
    float avs[4][4], avd[4][4];
#pragma unroll
    for (int ni = 0; ni < 4; ++ni)
#pragma unroll
        for (int r = 0; r < 4; ++r) {
            avs[ni][r] = attsv[ni * 16 + quad * 4 + r];
            avd[ni][r] = attdv[ni * 16 + quad * 4 + r];
        }
#pragma unroll
    for (int mi = 0; mi < 4; ++mi) {
        float ps = 0.f, pd = 0.f;
#pragma unroll
        for (int ni = 0; ni < 4; ++ni)
#pragma unroll
            for (int r = 0; r < 4; ++r) {
                ps += acc[mi][ni][r] * avs[ni][r];
                pd += acc[mi][ni][r] * avd[ni][r];
            }
        ps += __shfl_xor(ps, 16); ps += __shfl_xor(ps, 32);
        pd += __shfl_xor(pd, 16); pd += __shfl_xor(pd, 32);
        int m = m0 + wm * 64 + mi * 16 + row_m;
        if (quad == 0 && m < NN) {
            a_s[m * 4 + head] = ps;
            a_d[m * 4 + head] = pd;
        }
    }
}

// ---------------------------------------------------------------------------
// GAT softmax + aggregation, XCD-channel-sliced: block b = (node n = b>>1,
// half = b&1 -> channels [128*half, 128*half+128)). With round-robin
// blockIdx->XCD (bid%8), even XCDs touch only half 0 and odd XCDs half 1:
// per-XCD h-footprint halves (25.6 -> 12.8 MB) -> better L2 hit rate.
// Wave = 2 edge-groups of 32 lanes (edge jj / jj+1), each group covers the
// 128 channels via f16x4. Phase 1 computes only this half's 2 heads.
// Tails zero-filled so the pair loop needs no guards.
// ---------------------------------------------------------------------------
__global__ __launch_bounds__(64) void k_aggregate(
    const _Float16* __restrict__ h, const float* __restrict__ a_s,
    const float* __restrict__ a_d, const int* __restrict__ row_off,
    const int* __restrict__ csr_src, const float* __restrict__ bias,
    _Float16* __restrict__ out, int apply_elu) {
    const int b = blockIdx.x;
    const int n = b >> 1;
    const int half = b & 1;
    const int tid = threadIdx.x;              // 0..63
    const int eoff = tid >> 5;                // edge of the pair (0/1)
    const int ln = tid & 31;
    const int c4 = half * 128 + ln * 4;       // my 4 channels
    const int hl = ln >> 4;                   // head within half (0/1)
    const int start = row_off[n];
    const int end = row_off[n + 1];

    __shared__ float s_w[64][2];
    __shared__ int s_src[64];

    const float2 ad = *(const float2*)(a_d + (size_t)n * 4 + half * 2);

    float l0 = 0.f, l1 = 0.f;
    float4 acc = make_float4(0.f, 0.f, 0.f, 0.f);
    for (int base = start; base < end; base += 64) {
        int len = min(64, end - base);
        if (tid < len) {
            int s = csr_src[base + tid];
            const float2 as = *(const float2*)(a_s + (size_t)s * 4 + half * 2);
            float x0 = __expf(leaky(as.x + ad.x));
            float x1 = __expf(leaky(as.y + ad.y));
            l0 += x0; l1 += x1;
            s_src[tid] = s;
            s_w[tid][0] = x0; s_w[tid][1] = x1;
        } else {
            s_src[tid] = 0;
            s_w[tid][0] = 0.f; s_w[tid][1] = 0.f;
        }
        __syncthreads();
#pragma unroll 4
        for (int jj = 0; jj < len; jj += 2) {
            const int je = jj + eoff;
            const float wgt = s_w[je][hl];
            const f16x4 hv = *(const f16x4*)(h + (size_t)s_src[je] * D1 + c4);
            acc.x += wgt * (float)hv[0];
            acc.y += wgt * (float)hv[1];
            acc.z += wgt * (float)hv[2];
            acc.w += wgt * (float)hv[3];
        }
        __syncthreads();
    }
    // combine the edge pair halves (channel set depends only on ln)
    acc.x += __shfl_xor(acc.x, 32);
    acc.y += __shfl_xor(acc.y, 32);
    acc.z += __shfl_xor(acc.z, 32);
    acc.w += __shfl_xor(acc.w, 32);
    // denominators for this half's 2 heads (each edge counted once)
#pragma unroll
    for (int off = 32; off > 0; off >>= 1) {
        l0 += __shfl_xor(l0, off);
        l1 += __shfl_xor(l1, off);
    }

    if (tid < 32) {
        const float denom = (hl == 0) ? l0 : l1;
        const float inv = 1.f / denom;
        const float4 bb = *(const float4*)(bias + c4);
        float vx = acc.x * inv + bb.x;
        float vy = acc.y * inv + bb.y;
        float vz = acc.z * inv + bb.z;
        float vw = acc.w * inv + bb.w;
        if (apply_elu) {
            vx = vx > 0.f ? vx : expm1f(vx);
            vy = vy > 0.f ? vy : expm1f(vy);
            vz = vz > 0.f ? vz : expm1f(vz);
            vw = vw > 0.f ? vw : expm1f(vw);
        }
        f16x4 o;
        o[0] = (_Float16)vx; o[1] = (_Float16)vy; o[2] = (_Float16)vz; o[3] = (_Float16)vw;
        *(f16x4*)(out + (size_t)n * D1 + c4) = o;
    }
}

// ---------------------------------------------------------------------------
// Fused global mean pool + final FC: one 256-thr block per graph.
// batch is sorted -> binary search node range; channel-per-thread sum;
// then threads 0..63 compute the FC row.
// ---------------------------------------------------------------------------
__global__ __launch_bounds__(256) void k_pool_fc(const _Float16* __restrict__ h,
                                                 const int* __restrict__ batch,
                                                 const float* __restrict__ fc_w,
                                                 const float* __restrict__ fc_b,
                                                 float* __restrict__ out) {
    __shared__ float row[D1];
    int g = blockIdx.x, c = threadIdx.x;
    int lo = 0, hi = NN;
    while (lo < hi) { int mid = (lo + hi) >> 1; if (batch[mid] < g) lo = mid + 1; else hi = mid; }
    int start = lo;
    hi = NN;
    while (lo < hi) { int mid = (lo + hi) >> 1; if (batch[mid] < g + 1) lo = mid + 1; else hi = mid; }
    int end = lo;

    float acc = 0.f;
    for (int n = start; n < end; ++n) acc += (float)h[(size_t)n * D1 + c];
    float inv = 1.f / fmaxf((float)(end - start), 1.f);
    row[c] = acc * inv;
    __syncthreads();
    if (c < FOUT) {
        float o = 0.f;
#pragma unroll 4
        for (int k = 0; k < D1; ++k) o += row[k] * fc_w[k * FOUT + c];
        out[(size_t)g * FOUT + c] = o + fc_b[c];
    }
}

// ---------------------------------------------------------------------------
extern "C" void kernel_launch(void* const* d_in, const int* in_sizes, int n_in,
                              void* d_out, int out_size, void* d_ws, size_t ws_size,
                              hipStream_t stream) {
    const float* x        = (const float*)d_in[0];
    const int*   ei       = (const int*)d_in[1];
    const int*   batch    = (const int*)d_in[2];
    const float* W1       = (const float*)d_in[3];
    const float* att_src1 = (const float*)d_in[4];
    const float* att_dst1 = (const float*)d_in[5];
    const float* b1       = (const float*)d_in[6];
    const float* W2       = (const float*)d_in[7];
    const float* att_src2 = (const float*)d_in[8];
    const float* att_dst2 = (const float*)d_in[9];
    const float* b2       = (const float*)d_in[10];
    const float* fc_w     = (const float*)d_in[11];
    const float* fc_b     = (const float*)d_in[12];
    float* out = (float*)d_out;

    // workspace carve-up (~58 MB)
    _Float16* h_pre  = (_Float16*)d_ws;                       // NN*D1 f16
    _Float16* h_act  = h_pre + (size_t)NN * D1;               // NN*D1 f16
    _Float16* w1t    = h_act + (size_t)NN * D1;               // 256*128
    _Float16* w2t    = w1t + 256 * FIN;                       // 256*256
    float* a_s       = (float*)(w2t + 256 * D1);
    float* a_d       = a_s + (size_t)NN * 4;
    int*   deg       = (int*)(a_d + (size_t)NN * 4);
    int*   row_off   = deg + NN;
    int*   cursor    = row_off + NN + 1;
    int*   part      = cursor + NN;
    int*   csr_src   = part + 256;

    const int nblk_nodes = (NN + 255) / 256;
    const int nblk_edges = (EE + 255) / 256;
    const int nblk_etot  = (ETOT + 255) / 256;

    // ---- CSR build (6 small dispatches) ----
    hipMemsetAsync(deg, 0, NN * sizeof(int), stream);
    k_hist<<<nblk_edges, 256, 0, stream>>>(ei, deg);
    k_scan_blocks<<<nblk_nodes, 256, 0, stream>>>(deg, row_off, part);
    k_scan_part<<<1, 256, 0, stream>>>(part);
    k_add_off<<<nblk_nodes, 256, 0, stream>>>(row_off, part, cursor);
    k_scatter<<<nblk_etot, 256, 0, stream>>>(ei, cursor, csr_src);

    // ---- weight transposes (1 dispatch) ----
    k_cvt_w<<<(256 * (FIN + D1) + 255) / 256, 256, 0, stream>>>(W1, W2, w1t, w2t);

    dim3 ggrid((NN + BM - 1) / BM, D1 / BN);

    // ---- layer 1 (GEMM + fused logits) ----
    k_gemm<FIN, float><<<ggrid, 256, 0, stream>>>(x, w1t, h_pre,
                                                  att_src1, att_dst1, a_s, a_d);
    k_aggregate<<<2 * NN, 64, 0, stream>>>(h_pre, a_s, a_d, row_off, csr_src, b1, h_act, 1);

    // ---- layer 2 (GEMM + fused logits) ----
    k_gemm<D1, _Float16><<<ggrid, 256, 0, stream>>>(h_act, w2t, h_pre,
                                                    att_src2, att_dst2, a_s, a_d);
    k_aggregate<<<2 * NN, 64, 0, stream>>>(h_pre, a_s, a_d, row_off, csr_src, b2, h_act, 1);

    // ---- fused pool + fc ----
    k_pool_fc<<<NG, 256, 0, stream>>>(h_act, batch, fc_w, fc_b, out);
}